// Round 9
// baseline (403.399 us; speedup 1.0000x reference)
//
#include <hip/hip_runtime.h>

#define D 256
#define ROWS 32
#define NBLK 1024

typedef __attribute__((ext_vector_type(8))) short bf16x8;
typedef __attribute__((ext_vector_type(4))) float f32x4;

__device__ __forceinline__ unsigned short f2bf(float a) {
    unsigned int u = __float_as_uint(a);
    u = (u + 0x7fffu + ((u >> 16) & 1u)) >> 16;
    return (unsigned short)u;
}

__device__ __forceinline__ unsigned int cvt_pk_bf16(float a, float b) {
    unsigned int r;
    asm("v_cvt_pk_bf16_f32 %0, %1, %2" : "=v"(r) : "v"(a), "v"(b));
    return r;
}

__device__ __forceinline__ float fast_tanh(float v) {
    float a = __builtin_fabsf(v);
    float e = __builtin_amdgcn_exp2f(a * -2.88539008177793f);   // exp(-2a)
    float t = (1.0f - e) * __builtin_amdgcn_rcpf(1.0f + e);
    return __builtin_copysignf(t, v);
}

// ---------------------------------------------------------------------------
// Pack W1 (f32 [256][256], row k, col j) into bf16 MFMA b-frag layout.
// ---------------------------------------------------------------------------
__global__ void pack_w1_k(const float* __restrict__ W1, unsigned short* __restrict__ W1p) {
    int p = blockIdx.x * 256 + threadIdx.x;   // 0 .. 65535
    int e  = p & 7;
    int l  = (p >> 3) & 63;
    int cb = (p >> 9) & 15;
    int kk = p >> 13;
    int k   = 32 * kk + 8 * (l >> 4) + e;
    int col = 16 * cb + (l & 15);
    W1p[p] = f2bf(W1[k * D + col]);
}

__global__ void zero_k(float* __restrict__ p, int n) {
    int i = blockIdx.x * 256 + threadIdx.x;
    if (i < n) p[i] = 0.f;
}

// ---------------------------------------------------------------------------
// FLUSHX: emit accumulated (a4, den_p) for g_cur; compute next graph id -> gnv.
#define FLUSHX() do {                                                           \
    *reinterpret_cast<float4*>(&red[w][l * 4]) = a4;                            \
    int _m8 = 0x7fffffff;                                                       \
    _Pragma("unroll")                                                           \
    for (int _it = 0; _it < 8; ++_it)                                           \
        if (bg[_it] > g_cur && bg[_it] < _m8) _m8 = bg[_it];                    \
    _m8 = min(_m8, __shfl_xor(_m8, 1));  _m8 = min(_m8, __shfl_xor(_m8, 2));    \
    _m8 = min(_m8, __shfl_xor(_m8, 4));  _m8 = min(_m8, __shfl_xor(_m8, 8));    \
    _m8 = min(_m8, __shfl_xor(_m8, 16)); _m8 = min(_m8, __shfl_xor(_m8, 32));   \
    float _dw = den_p;                                                          \
    _dw += __shfl_xor(_dw, 1);  _dw += __shfl_xor(_dw, 2);                      \
    _dw += __shfl_xor(_dw, 4);  _dw += __shfl_xor(_dw, 8);                      \
    _dw += __shfl_xor(_dw, 16); _dw += __shfl_xor(_dw, 32);                     \
    if (l == 0) { gmin4[w] = _m8; denw[w] = _dw; }                              \
    __syncthreads();                                                            \
    { const float _fs = red[0][tid] + red[1][tid] + red[2][tid] + red[3][tid];  \
      atomicAdd(&accb[(size_t)g_cur * D + tid], _fs); }                         \
    if (tid == 0)                                                               \
        atomicAdd(&den[g_cur], (denw[0] + denw[1] + denw[2] + denw[3]) * 0.015625f); \
    gnv = min(min(gmin4[0], gmin4[1]), min(gmin4[2], gmin4[3]));                \
    a4 = make_float4(0.f, 0.f, 0.f, 0.f); den_p = 0.f;                          \
    __syncthreads();                                                            \
} while (0)

// BODY: one 32-row tile, no x staging. A-frags + pool straight from global
// (tile is L1-resident: 32 KB). W1p from L2 with 1-deep prefetch (no async
// stage queue to drain -> no R8 vmcnt trap). 2 barriers/tile (+2 per flush).
#define BODY() do {                                                             \
    const int _row0 = t * ROWS;                                                 \
    _Pragma("unroll")                                                           \
    for (int _it = 0; _it < 8; ++_it) {                                         \
        int _ri = _row0 + 4 * _it + w;                                          \
        bg[_it] = batch[_ri < N ? _ri : N - 1];                                 \
    }                                                                           \
    const int g0u = batch[_row0];                                               \
    int _gli = _row0 + ROWS - 1;                                                \
    const int glast = batch[_gli < N ? _gli : N - 1];                           \
    /* ---- scores: tanh(x@W1+b1)@W2+b2 ; A from global x, B from L2 ---- */    \
    f32x4 acc[2][4];                                                            \
    _Pragma("unroll")                                                           \
    for (int _m = 0; _m < 2; ++_m)                                              \
        _Pragma("unroll")                                                       \
        for (int _n = 0; _n < 4; ++_n) acc[_m][_n] = (f32x4){0.f, 0.f, 0.f, 0.f}; \
    /* row base (clamped for tail tiles; garbage rows masked by erow=0) */      \
    const float4* _xr0 = x4 + (size_t)min(_row0 +      l15, N - 1) * 64;        \
    const float4* _xr1 = x4 + (size_t)min(_row0 + 16 + l15, N - 1) * 64;        \
    bf16x8 _bc[4], _bn[4];                                                      \
    _Pragma("unroll")                                                           \
    for (int _n = 0; _n < 4; ++_n)                                              \
        _bc[_n] = *reinterpret_cast<const bf16x8*>(                             \
            W1p + (size_t)((w * 4 + _n) * 64 + l) * 8);                         \
    _Pragma("unroll")                                                           \
    for (int _kk = 0; _kk < 8; ++_kk) {                                         \
        if (_kk < 7) {                                                          \
            _Pragma("unroll")                                                   \
            for (int _n = 0; _n < 4; ++_n)                                      \
                _bn[_n] = *reinterpret_cast<const bf16x8*>(                     \
                    W1p + (size_t)((((_kk + 1) * 16) + (w * 4 + _n)) * 64 + l) * 8); \
        }                                                                       \
        bf16x8 _afr[2];                                                         \
        _Pragma("unroll")                                                       \
        for (int _m = 0; _m < 2; ++_m) {                                        \
            const float4* _xr = _m ? _xr1 : _xr0;                               \
            const float4 _f0 = _xr[_kk * 8 + g4 * 2];                           \
            const float4 _f1 = _xr[_kk * 8 + g4 * 2 + 1];                       \
            uint4 _u;                                                           \
            _u.x = cvt_pk_bf16(_f0.x, _f0.y); _u.y = cvt_pk_bf16(_f0.z, _f0.w); \
            _u.z = cvt_pk_bf16(_f1.x, _f1.y); _u.w = cvt_pk_bf16(_f1.z, _f1.w); \
            _afr[_m] = *reinterpret_cast<bf16x8*>(&_u);                         \
        }                                                                       \
        _Pragma("unroll")                                                       \
        for (int _m = 0; _m < 2; ++_m)                                          \
            _Pragma("unroll")                                                   \
            for (int _n = 0; _n < 4; ++_n)                                      \
                acc[_m][_n] = __builtin_amdgcn_mfma_f32_16x16x32_bf16(          \
                    _afr[_m], _bc[_n], acc[_m][_n], 0, 0, 0);                   \
        if (_kk < 7) {                                                          \
            _Pragma("unroll")                                                   \
            for (int _n = 0; _n < 4; ++_n) _bc[_n] = _bn[_n];                   \
        }                                                                       \
    }                                                                           \
    /* ---- epilogue: +b1, tanh, *W2, 16-lane reduce -> scpart ---- */          \
    {                                                                           \
        float _part[2][4];                                                      \
        _Pragma("unroll")                                                       \
        for (int _m = 0; _m < 2; ++_m)                                          \
            _Pragma("unroll")                                                   \
            for (int _r = 0; _r < 4; ++_r) _part[_m][_r] = 0.f;                 \
        _Pragma("unroll")                                                       \
        for (int _n = 0; _n < 4; ++_n)                                          \
            _Pragma("unroll")                                                   \
            for (int _m = 0; _m < 2; ++_m)                                      \
                _Pragma("unroll")                                               \
                for (int _r = 0; _r < 4; ++_r) {                                \
                    float _h = fast_tanh(acc[_m][_n][_r] + b1v[_n]);            \
                    _part[_m][_r] += _h * w2v[_n];                              \
                }                                                               \
        _Pragma("unroll")                                                       \
        for (int _m = 0; _m < 2; ++_m)                                          \
            _Pragma("unroll")                                                   \
            for (int _r = 0; _r < 4; ++_r) {                                    \
                float _p = _part[_m][_r];                                       \
                _p += __shfl_xor(_p, 8, 16); _p += __shfl_xor(_p, 4, 16);       \
                _p += __shfl_xor(_p, 2, 16); _p += __shfl_xor(_p, 1, 16);       \
                if (l15 == 0) scpart[w][16 * _m + 4 * g4 + _r] = _p;            \
            }                                                                   \
    }                                                                           \
    __syncthreads();                                                            \
    if (tid < 32) {                                                             \
        float _s = scpart[0][tid] + scpart[1][tid] + scpart[2][tid] + scpart[3][tid] + b2v; \
        erow[tid] = ((_row0 + tid) < N)                                         \
                  ? __builtin_amdgcn_exp2f(_s * 1.4426950408889634f) : 0.f;     \
    }                                                                           \
    __syncthreads();                                                            \
    /* ---- pool: coalesced L1-hot re-read of the tile rows ---- */             \
    {                                                                           \
        float4 pv[8];                                                           \
        _Pragma("unroll")                                                       \
        for (int _it = 0; _it < 8; ++_it) {                                     \
            int _ri = _row0 + 4 * _it + w;                                      \
            _ri = (_ri < N) ? _ri : (N - 1);                                    \
            pv[_it] = x4[(size_t)_ri * 64 + l];                                 \
        }                                                                       \
        if (g_cur < 0) g_cur = g0u;                                             \
        while (true) {                                                          \
            _Pragma("unroll")                                                   \
            for (int _it = 0; _it < 8; ++_it) {                                 \
                const float _e = (bg[_it] == g_cur) ? erow[4 * _it + w] : 0.f;  \
                a4.x += _e * pv[_it].x; a4.y += _e * pv[_it].y;                 \
                a4.z += _e * pv[_it].z; a4.w += _e * pv[_it].w;                 \
                den_p += _e;                                                    \
            }                                                                   \
            if (glast <= g_cur) break;                                          \
            FLUSHX();                                                           \
            g_cur = gnv;                                                        \
        }                                                                       \
    }                                                                           \
    ++t;                                                                        \
} while (0)

// ---------------------------------------------------------------------------
// Persistent fused kernel, NO x LDS staging: A-fragments converted on the fly
// from global x (tile = 32 KB = L1-resident; all waves share lines), pooling
// re-reads the same L1-hot rows coalesced. LDS ~4.5 KB. W1p streamed from L2
// with 1-deep prefetch. No launch_bounds min-waves (spill demon r2/r6); no
// sched_barrier pinning (compiler schedules the kk-loop freely).
// ---------------------------------------------------------------------------
__global__ void __launch_bounds__(256)
fused_k(const float* __restrict__ x,
        const unsigned short* __restrict__ W1p,
        const float* __restrict__ b1,
        const float* __restrict__ W2,
        const float* __restrict__ b2,
        const int* __restrict__ batch,
        int N, int NT,
        float* __restrict__ accb, float* __restrict__ den) {
    __shared__ __align__(16) float red[4][256];
    __shared__ float scpart[4][32];
    __shared__ float erow[32];
    __shared__ int   gmin4[4];
    __shared__ float denw[4];

    const int tid = threadIdx.x;
    const int w   = tid >> 6;
    const int l   = tid & 63;
    const int l15 = l & 15;
    const int g4  = l >> 4;

    const int tpb = (NT + NBLK - 1) / NBLK;
    int t = blockIdx.x * tpb;
    const int t1 = min(NT, t + tpb);
    if (t >= t1) return;

    float b1v[4], w2v[4];
    #pragma unroll
    for (int n = 0; n < 4; ++n) {
        int col = 64 * w + 16 * n + l15;
        b1v[n] = b1[col];
        w2v[n] = W2[col];
    }
    const float b2v = b2[0];

    const float4* x4 = reinterpret_cast<const float4*>(x);

    float4 a4 = make_float4(0.f, 0.f, 0.f, 0.f);
    float den_p = 0.f;
    int g_cur = -1;
    int gnv = 0;
    int bg[8];   // kernel scope: final FLUSHX uses last body's values

    while (t < t1) {
        BODY();
    }

    FLUSHX();   // final graph
}

// ---------------------------------------------------------------------------
__global__ void __launch_bounds__(256)
norm_k(const float* __restrict__ accb, const float* __restrict__ den,
       float* __restrict__ out) {
    int g = blockIdx.x;
    float dv = den[g];
    float inv = (dv > 0.f) ? 1.0f / dv : 0.f;
    out[(size_t)g * D + threadIdx.x] = accb[(size_t)g * D + threadIdx.x] * inv;
}

// ---------------------------------------------------------------------------
extern "C" void kernel_launch(void* const* d_in, const int* in_sizes, int n_in,
                              void* d_out, int out_size, void* d_ws, size_t ws_size,
                              hipStream_t stream) {
    const float* x     = (const float*)d_in[0];
    const int*   batch = (const int*)d_in[1];
    const float* W1    = (const float*)d_in[3];
    const float* b1    = (const float*)d_in[4];
    const float* W2    = (const float*)d_in[5];
    const float* b2    = (const float*)d_in[6];
    float* out = (float*)d_out;

    const int N = in_sizes[0] / D;
    const int G = out_size / D;
    const int NT = (N + ROWS - 1) / ROWS;

    char* ws = (char*)d_ws;
    unsigned short* W1p = (unsigned short*)ws;               // 128 KB
    float* accb = (float*)(ws + 131072);                     // G*D*4 bytes
    float* den  = (float*)(ws + 131072 + (size_t)G * D * 4); // G*4, contiguous

    zero_k<<<dim3((G * D + G + 255) / 256), dim3(256), 0, stream>>>(accb, G * D + G);
    pack_w1_k<<<dim3(256), dim3(256), 0, stream>>>(W1, W1p);
    fused_k<<<dim3(min(NBLK, NT)), dim3(256), 0, stream>>>(x, W1p, b1, W2, b2, batch,
                                                           N, NT, accb, den);
    norm_k<<<dim3(G), dim3(256), 0, stream>>>(accb, den, out);
}

// Round 10
// 215.401 us; speedup vs baseline: 1.8728x; 1.8728x over previous
//
#include <hip/hip_runtime.h>

#define D 256
#define ROWS 32
#define NBLK 1024

typedef __attribute__((ext_vector_type(8))) short bf16x8;
typedef __attribute__((ext_vector_type(4))) float f32x4;

__device__ __forceinline__ unsigned short f2bf(float a) {
    unsigned int u = __float_as_uint(a);
    u = (u + 0x7fffu + ((u >> 16) & 1u)) >> 16;
    return (unsigned short)u;
}

__device__ __forceinline__ unsigned int cvt_pk_bf16(float a, float b) {
    unsigned int r;
    asm("v_cvt_pk_bf16_f32 %0, %1, %2" : "=v"(r) : "v"(a), "v"(b));
    return r;
}

__device__ __forceinline__ float fast_tanh(float v) {
    float a = __builtin_fabsf(v);
    float e = __builtin_amdgcn_exp2f(a * -2.88539008177793f);   // exp(-2a)
    float t = (1.0f - e) * __builtin_amdgcn_rcpf(1.0f + e);
    return __builtin_copysignf(t, v);
}

// Swizzled byte offset into the f32 x-tile (k-major transposed):
// chunk c = col8 (0..31), row r (0..31), 16B-half q (0..1).
__device__ __forceinline__ int xf_off(int c, int r, int q) {
    return ((c << 10) + (r << 5) + (q << 4)) ^ ((c & 3) << 5) ^ ((r & 4) << 2);
}

__device__ __forceinline__ void gload_lds16(const void* g, void* l) {
    __builtin_amdgcn_global_load_lds(
        (const __attribute__((address_space(1))) unsigned int*)g,
        (__attribute__((address_space(3))) unsigned int*)l, 16, 0, 0);
}

// ---------------------------------------------------------------------------
__global__ void pack_w1_k(const float* __restrict__ W1, unsigned short* __restrict__ W1p) {
    int p = blockIdx.x * 256 + threadIdx.x;   // 0 .. 65535
    int e  = p & 7;
    int l  = (p >> 3) & 63;
    int cb = (p >> 9) & 15;
    int kk = p >> 13;
    int k   = 32 * kk + 8 * (l >> 4) + e;
    int col = 16 * cb + (l & 15);
    W1p[p] = f2bf(W1[k * D + col]);
}

__global__ void zero_k(float* __restrict__ p, int n) {
    int i = blockIdx.x * 256 + threadIdx.x;
    if (i < n) p[i] = 0.f;
}

// ---------------------------------------------------------------------------
// STAGE: async global->LDS of one 32x256 f32 tile, linear LDS dest,
// inverse-swizzled per-lane global source (so swizzled reads see x[r][8c..]).
#define STAGE(XN, tn) do {                                                      \
    const int _r0s = (tn) * ROWS;                                               \
    _Pragma("unroll")                                                           \
    for (int _it = 0; _it < 8; ++_it) {                                         \
        const int _c = _it * 4 + w;                                             \
        const int _r = (l >> 1) ^ (_c & 3);                                     \
        const int _q = (l & 1) ^ ((_r >> 2) & 1);                               \
        int _row = _r0s + _r; _row = (_row < N) ? _row : (N - 1);               \
        gload_lds16((const char*)x + ((size_t)_row << 10) + (size_t)(((_c << 1) + _q) << 4), \
                    (char*)(XN) + (_it << 12) + (w << 10) + (l << 4));          \
    }                                                                           \
} while (0)

// FLUSHX: emit accumulated (a4, den_p) for g_cur; compute next graph id -> gnv.
#define FLUSHX() do {                                                           \
    *reinterpret_cast<float4*>(&red[w][l * 4]) = a4;                            \
    int _m8 = 0x7fffffff;                                                       \
    _Pragma("unroll")                                                           \
    for (int _it = 0; _it < 8; ++_it)                                           \
        if (bg[_it] > g_cur && bg[_it] < _m8) _m8 = bg[_it];                    \
    _m8 = min(_m8, __shfl_xor(_m8, 1));  _m8 = min(_m8, __shfl_xor(_m8, 2));    \
    _m8 = min(_m8, __shfl_xor(_m8, 4));  _m8 = min(_m8, __shfl_xor(_m8, 8));    \
    _m8 = min(_m8, __shfl_xor(_m8, 16)); _m8 = min(_m8, __shfl_xor(_m8, 32));   \
    float _dw = den_p;                                                          \
    _dw += __shfl_xor(_dw, 1);  _dw += __shfl_xor(_dw, 2);                      \
    _dw += __shfl_xor(_dw, 4);  _dw += __shfl_xor(_dw, 8);                      \
    _dw += __shfl_xor(_dw, 16); _dw += __shfl_xor(_dw, 32);                     \
    if (l == 0) { gmin4[w] = _m8; denw[w] = _dw; }                              \
    __syncthreads();                                                            \
    { const float _fs = red[0][tid] + red[1][tid] + red[2][tid] + red[3][tid];  \
      atomicAdd(&accb[(size_t)g_cur * D + tid], _fs); }                         \
    if (tid == 0)                                                               \
        atomicAdd(&den[g_cur], (denw[0] + denw[1] + denw[2] + denw[3]) * 0.015625f); \
    gnv = min(min(gmin4[0], gmin4[1]), min(gmin4[2], gmin4[3]));                \
    a4 = make_float4(0.f, 0.f, 0.f, 0.f); den_p = 0.f;                          \
    __syncthreads();                                                            \
} while (0)

// BODY: tile t is in the single LDS buffer Xf (staged at end of prev body).
// kk-loop has an EMPTY async queue underneath it (single buffer, stage issued
// post-pool), so in-loop W1p L2 loads wait only on themselves (no R8 trap).
#define BODY() do {                                                             \
    const int _row0 = t * ROWS;                                                 \
    _Pragma("unroll")                                                           \
    for (int _it = 0; _it < 8; ++_it) {                                         \
        int _ri = _row0 + 4 * _it + w;                                          \
        bg[_it] = batch[_ri < N ? _ri : N - 1];                                 \
    }                                                                           \
    const int g0u = batch[_row0];                                               \
    int _gli = _row0 + ROWS - 1;                                                \
    const int glast = batch[_gli < N ? _gli : N - 1];                           \
    asm volatile("s_waitcnt vmcnt(0)" ::: "memory");  /* stage of t complete */ \
    __syncthreads();                                                            \
    /* ---- scores: tanh(x@W1+b1)@W2+b2 ; A from LDS f32+cvt, B from L2 ---- */ \
    f32x4 acc[2][4];                                                            \
    _Pragma("unroll")                                                           \
    for (int _m = 0; _m < 2; ++_m)                                              \
        _Pragma("unroll")                                                       \
        for (int _n = 0; _n < 4; ++_n) acc[_m][_n] = (f32x4){0.f, 0.f, 0.f, 0.f}; \
    bf16x8 _bc[4], _bn[4];                                                      \
    _Pragma("unroll")                                                           \
    for (int _n = 0; _n < 4; ++_n)                                              \
        _bc[_n] = *reinterpret_cast<const bf16x8*>(                             \
            W1p + (size_t)((w * 4 + _n) * 64 + l) * 8);                         \
    _Pragma("unroll")                                                           \
    for (int _kk = 0; _kk < 8; ++_kk) {                                         \
        if (_kk < 7) {                                                          \
            _Pragma("unroll")                                                   \
            for (int _n = 0; _n < 4; ++_n)                                      \
                _bn[_n] = *reinterpret_cast<const bf16x8*>(                     \
                    W1p + (size_t)((((_kk + 1) * 16) + (w * 4 + _n)) * 64 + l) * 8); \
        }                                                                       \
        bf16x8 _afr[2];                                                         \
        _Pragma("unroll")                                                       \
        for (int _m = 0; _m < 2; ++_m) {                                        \
            const int _rr = 16 * _m + l15;                                      \
            const int _cc = 4 * _kk + g4;                                       \
            const int _o0 = xf_off(_cc, _rr, 0);                                \
            const float4 _f0 = *reinterpret_cast<const float4*>(xb + _o0);      \
            const float4 _f1 = *reinterpret_cast<const float4*>(xb + (_o0 ^ 16)); \
            uint4 _u;                                                           \
            _u.x = cvt_pk_bf16(_f0.x, _f0.y); _u.y = cvt_pk_bf16(_f0.z, _f0.w); \
            _u.z = cvt_pk_bf16(_f1.x, _f1.y); _u.w = cvt_pk_bf16(_f1.z, _f1.w); \
            _afr[_m] = *reinterpret_cast<bf16x8*>(&_u);                         \
        }                                                                       \
        _Pragma("unroll")                                                       \
        for (int _m = 0; _m < 2; ++_m)                                          \
            _Pragma("unroll")                                                   \
            for (int _n = 0; _n < 4; ++_n)                                      \
                acc[_m][_n] = __builtin_amdgcn_mfma_f32_16x16x32_bf16(          \
                    _afr[_m], _bc[_n], acc[_m][_n], 0, 0, 0);                   \
        if (_kk < 7) {                                                          \
            _Pragma("unroll")                                                   \
            for (int _n = 0; _n < 4; ++_n) _bc[_n] = _bn[_n];                   \
        }                                                                       \
    }                                                                           \
    /* ---- epilogue: +b1, tanh, *W2, 16-lane reduce -> scpart ---- */          \
    {                                                                           \
        float _part[2][4];                                                      \
        _Pragma("unroll")                                                       \
        for (int _m = 0; _m < 2; ++_m)                                          \
            _Pragma("unroll")                                                   \
            for (int _r = 0; _r < 4; ++_r) _part[_m][_r] = 0.f;                 \
        _Pragma("unroll")                                                       \
        for (int _n = 0; _n < 4; ++_n)                                          \
            _Pragma("unroll")                                                   \
            for (int _m = 0; _m < 2; ++_m)                                      \
                _Pragma("unroll")                                               \
                for (int _r = 0; _r < 4; ++_r) {                                \
                    float _h = fast_tanh(acc[_m][_n][_r] + b1v[_n]);            \
                    _part[_m][_r] += _h * w2v[_n];                              \
                }                                                               \
        _Pragma("unroll")                                                       \
        for (int _m = 0; _m < 2; ++_m)                                          \
            _Pragma("unroll")                                                   \
            for (int _r = 0; _r < 4; ++_r) {                                    \
                float _p = _part[_m][_r];                                       \
                _p += __shfl_xor(_p, 8, 16); _p += __shfl_xor(_p, 4, 16);       \
                _p += __shfl_xor(_p, 2, 16); _p += __shfl_xor(_p, 1, 16);       \
                if (l15 == 0) scpart[w][16 * _m + 4 * g4 + _r] = _p;            \
            }                                                                   \
    }                                                                           \
    __syncthreads();                                                            \
    if (tid < 32) {                                                             \
        float _s = scpart[0][tid] + scpart[1][tid] + scpart[2][tid] + scpart[3][tid] + b2v; \
        erow[tid] = ((_row0 + tid) < N)                                         \
                  ? __builtin_amdgcn_exp2f(_s * 1.4426950408889634f) : 0.f;     \
    }                                                                           \
    __syncthreads();                                                            \
    /* ---- pool: exact f32 from the LDS tile; flush on graph change ---- */    \
    if (g_cur < 0) g_cur = g0u;                                                 \
    while (true) {                                                              \
        _Pragma("unroll")                                                       \
        for (int _it = 0; _it < 8; ++_it) {                                     \
            const int _r = 4 * _it + w;                                         \
            const float _e = (bg[_it] == g_cur) ? erow[_r] : 0.f;               \
            const float4 _v = *reinterpret_cast<const float4*>(                 \
                xb + xf_off(l >> 1, _r, l & 1));                                \
            a4.x += _e * _v.x; a4.y += _e * _v.y;                               \
            a4.z += _e * _v.z; a4.w += _e * _v.w;                               \
            den_p += _e;                                                        \
        }                                                                       \
        if (glast <= g_cur) break;                                              \
        FLUSHX();                                                               \
        g_cur = gnv;                                                            \
    }                                                                           \
    __syncthreads();   /* all pool reads of the buffer done */                  \
    if (t + 1 < t1) STAGE(Xf, t + 1);   /* refill; waited at next body top */   \
    ++t;                                                                        \
} while (0)

// ---------------------------------------------------------------------------
// Persistent fused kernel, SINGLE 32KB f32 LDS buffer -> 37.5KB LDS and
// ~128 VGPR (no W1p reg cache) -> up to 4 blocks/CU. The per-tile chain is
// unchanged from R5 but 4-way block-interleaved instead of 2-way; the
// exposed single-buffer stage latency is covered by the other blocks.
// ---------------------------------------------------------------------------
__global__ void __launch_bounds__(256)
fused_k(const float* __restrict__ x,
        const unsigned short* __restrict__ W1p,
        const float* __restrict__ b1,
        const float* __restrict__ W2,
        const float* __restrict__ b2,
        const int* __restrict__ batch,
        int N, int NT,
        float* __restrict__ accb, float* __restrict__ den) {
    __shared__ __align__(16) char Xf[32768];
    __shared__ __align__(16) float red[4][256];
    __shared__ float scpart[4][32];
    __shared__ float erow[32];
    __shared__ int   gmin4[4];
    __shared__ float denw[4];

    const int tid = threadIdx.x;
    const int w   = tid >> 6;
    const int l   = tid & 63;
    const int l15 = l & 15;
    const int g4  = l >> 4;
    char* xb = Xf;

    const int tpb = (NT + NBLK - 1) / NBLK;
    int t = blockIdx.x * tpb;
    const int t1 = min(NT, t + tpb);
    if (t >= t1) return;

    float b1v[4], w2v[4];
    #pragma unroll
    for (int n = 0; n < 4; ++n) {
        int col = 64 * w + 16 * n + l15;
        b1v[n] = b1[col];
        w2v[n] = W2[col];
    }
    const float b2v = b2[0];

    // prologue: stage first tile
    STAGE(Xf, t);

    float4 a4 = make_float4(0.f, 0.f, 0.f, 0.f);
    float den_p = 0.f;
    int g_cur = -1;
    int gnv = 0;
    int bg[8];   // kernel scope: final FLUSHX uses last body's values

    while (t < t1) {
        BODY();
    }

    FLUSHX();   // final graph
}

// ---------------------------------------------------------------------------
__global__ void __launch_bounds__(256)
norm_k(const float* __restrict__ accb, const float* __restrict__ den,
       float* __restrict__ out) {
    int g = blockIdx.x;
    float dv = den[g];
    float inv = (dv > 0.f) ? 1.0f / dv : 0.f;
    out[(size_t)g * D + threadIdx.x] = accb[(size_t)g * D + threadIdx.x] * inv;
}

// ---------------------------------------------------------------------------
extern "C" void kernel_launch(void* const* d_in, const int* in_sizes, int n_in,
                              void* d_out, int out_size, void* d_ws, size_t ws_size,
                              hipStream_t stream) {
    const float* x     = (const float*)d_in[0];
    const int*   batch = (const int*)d_in[1];
    const float* W1    = (const float*)d_in[3];
    const float* b1    = (const float*)d_in[4];
    const float* W2    = (const float*)d_in[5];
    const float* b2    = (const float*)d_in[6];
    float* out = (float*)d_out;

    const int N = in_sizes[0] / D;
    const int G = out_size / D;
    const int NT = (N + ROWS - 1) / ROWS;

    char* ws = (char*)d_ws;
    unsigned short* W1p = (unsigned short*)ws;               // 128 KB
    float* accb = (float*)(ws + 131072);                     // G*D*4 bytes
    float* den  = (float*)(ws + 131072 + (size_t)G * D * 4); // G*4, contiguous

    zero_k<<<dim3((G * D + G + 255) / 256), dim3(256), 0, stream>>>(accb, G * D + G);
    pack_w1_k<<<dim3(256), dim3(256), 0, stream>>>(W1, W1p);
    fused_k<<<dim3(min(NBLK, NT)), dim3(256), 0, stream>>>(x, W1p, b1, W2, b2, batch,
                                                           N, NT, accb, den);
    norm_k<<<dim3(G), dim3(256), 0, stream>>>(accb, den, out);
}

// Round 11
// 201.289 us; speedup vs baseline: 2.0041x; 1.0701x over previous
//
#include <hip/hip_runtime.h>

#define D 256
#define ROWS 32
#define NBLK 512

typedef __attribute__((ext_vector_type(8))) short bf16x8;
typedef __attribute__((ext_vector_type(4))) float f32x4;

__device__ __forceinline__ unsigned short f2bf(float a) {
    unsigned int u = __float_as_uint(a);
    u = (u + 0x7fffu + ((u >> 16) & 1u)) >> 16;
    return (unsigned short)u;
}

__device__ __forceinline__ unsigned int cvt_pk_bf16(float a, float b) {
    unsigned int r;
    asm("v_cvt_pk_bf16_f32 %0, %1, %2" : "=v"(r) : "v"(a), "v"(b));
    return r;
}

__device__ __forceinline__ float fast_tanh(float v) {
    float a = __builtin_fabsf(v);
    float e = __builtin_amdgcn_exp2f(a * -2.88539008177793f);   // exp(-2a)
    float t = (1.0f - e) * __builtin_amdgcn_rcpf(1.0f + e);
    return __builtin_copysignf(t, v);
}

// Swizzled byte offset into the f32 x-tile (k-major transposed):
// chunk c = col8 (0..31), row r (0..31), 16B-half q (0..1).
__device__ __forceinline__ int xf_off(int c, int r, int q) {
    return ((c << 10) + (r << 5) + (q << 4)) ^ ((c & 3) << 5) ^ ((r & 4) << 2);
}

__device__ __forceinline__ void gload_lds16(const void* g, void* l) {
    __builtin_amdgcn_global_load_lds(
        (const __attribute__((address_space(1))) unsigned int*)g,
        (__attribute__((address_space(3))) unsigned int*)l, 16, 0, 0);
}

// ---------------------------------------------------------------------------
__global__ void pack_w1_k(const float* __restrict__ W1, unsigned short* __restrict__ W1p) {
    int p = blockIdx.x * 256 + threadIdx.x;   // 0 .. 65535
    int e  = p & 7;
    int l  = (p >> 3) & 63;
    int cb = (p >> 9) & 15;
    int kk = p >> 13;
    int k   = 32 * kk + 8 * (l >> 4) + e;
    int col = 16 * cb + (l & 15);
    W1p[p] = f2bf(W1[k * D + col]);
}

__global__ void zero_k(float* __restrict__ p, int n) {
    int i = blockIdx.x * 256 + threadIdx.x;
    if (i < n) p[i] = 0.f;
}

// ---------------------------------------------------------------------------
// STAGE: async global->LDS of one 32x256 f32 tile, linear LDS dest,
// inverse-swizzled per-lane global source (so swizzled reads see x[r][8c..]).
#define STAGE(XN, tn) do {                                                      \
    const int _r0s = (tn) * ROWS;                                               \
    _Pragma("unroll")                                                           \
    for (int _it = 0; _it < 8; ++_it) {                                         \
        const int _c = _it * 4 + w;                                             \
        const int _r = (l >> 1) ^ (_c & 3);                                     \
        const int _q = (l & 1) ^ ((_r >> 2) & 1);                               \
        int _row = _r0s + _r; _row = (_row < N) ? _row : (N - 1);               \
        gload_lds16((const char*)x + ((size_t)_row << 10) + (size_t)(((_c << 1) + _q) << 4), \
                    (char*)(XN) + (_it << 12) + (w << 10) + (l << 4));          \
    }                                                                           \
} while (0)

// FLUSHX: emit accumulated (a4, den_p) for g_cur; compute next graph id -> gnv.
#define FLUSHX() do {                                                           \
    *reinterpret_cast<float4*>(&red[w][l * 4]) = a4;                            \
    int _m8 = 0x7fffffff;                                                       \
    _Pragma("unroll")                                                           \
    for (int _it = 0; _it < 8; ++_it)                                           \
        if (bg[_it] > g_cur && bg[_it] < _m8) _m8 = bg[_it];                    \
    _m8 = min(_m8, __shfl_xor(_m8, 1));  _m8 = min(_m8, __shfl_xor(_m8, 2));    \
    _m8 = min(_m8, __shfl_xor(_m8, 4));  _m8 = min(_m8, __shfl_xor(_m8, 8));    \
    _m8 = min(_m8, __shfl_xor(_m8, 16)); _m8 = min(_m8, __shfl_xor(_m8, 32));   \
    float _dw = den_p;                                                          \
    _dw += __shfl_xor(_dw, 1);  _dw += __shfl_xor(_dw, 2);                      \
    _dw += __shfl_xor(_dw, 4);  _dw += __shfl_xor(_dw, 8);                      \
    _dw += __shfl_xor(_dw, 16); _dw += __shfl_xor(_dw, 32);                     \
    if (l == 0) { gmin4[w] = _m8; denw[w] = _dw; }                              \
    asm volatile("s_waitcnt lgkmcnt(0)" ::: "memory");                          \
    __builtin_amdgcn_sched_barrier(0);                                          \
    __builtin_amdgcn_s_barrier();                                               \
    __builtin_amdgcn_sched_barrier(0);                                          \
    { const float _fs = red[0][tid] + red[1][tid] + red[2][tid] + red[3][tid];  \
      atomicAdd(&accb[(size_t)g_cur * D + tid], _fs); }                         \
    if (tid == 0)                                                               \
        atomicAdd(&den[g_cur], (denw[0] + denw[1] + denw[2] + denw[3]) * 0.015625f); \
    gnv = min(min(gmin4[0], gmin4[1]), min(gmin4[2], gmin4[3]));                \
    a4 = make_float4(0.f, 0.f, 0.f, 0.f); den_p = 0.f;                          \
    __builtin_amdgcn_s_barrier();                                               \
    __builtin_amdgcn_sched_barrier(0);                                          \
} while (0)

// POOL: accumulate this tile's rows into (a4, den_p) using hoisted _ev[],
// flushing on graph change. Row r handled by all 64 lanes of wave r%4 ->
// den scaled by 1/64 at flush.
#define POOL(XC) do {                                                           \
    if (g_cur < 0) g_cur = g0u;                                                 \
    while (true) {                                                              \
        _Pragma("unroll")                                                       \
        for (int _it = 0; _it < 8; ++_it) {                                     \
            const int _r = 4 * _it + w;                                         \
            const float _e = (bg[_it] == g_cur) ? _ev[_it] : 0.f;               \
            const float4 _v = *reinterpret_cast<const float4*>(                 \
                (const char*)(XC) + xf_off(l >> 1, _r, l & 1));                 \
            a4.x += _e * _v.x; a4.y += _e * _v.y;                               \
            a4.z += _e * _v.z; a4.w += _e * _v.w;                               \
            den_p += _e;                                                        \
        }                                                                       \
        if (glast <= g_cur) break;                                              \
        FLUSHX();                                                               \
        g_cur = gnv;                                                            \
    }                                                                           \
} while (0)

// BODY: process tile t from XC, prefetch tile t+1 into XN. ++t at end.
// Score cross-wave reduce via LDS float atomics into parity buffer srow[t&1]
// (zeroed one body ahead); exp applied inline in the pool prep. 3 raw-barrier
// trios per body (was 4), no 32-thread serial phase.
#define BODY(XC, XN) do {                                                       \
    const int _row0 = t * ROWS;                                                 \
    const int _pp = t & 1;                                                      \
    _Pragma("unroll")                                                           \
    for (int _it = 0; _it < 8; ++_it) {                                         \
        int _ri = _row0 + 4 * _it + w;                                          \
        bg[_it] = batch[_ri < N ? _ri : N - 1];                                 \
    }                                                                           \
    const int g0u = batch[_row0];                                               \
    int _gli = _row0 + 31;                                                      \
    const int glast = batch[_gli < N ? _gli : N - 1];                           \
    __builtin_amdgcn_sched_barrier(0);                                          \
    const bool _hn = (t + 1 < t1);                                              \
    if (_hn) {                                                                  \
        STAGE(XN, t + 1);                                                       \
        asm volatile("s_waitcnt vmcnt(8) lgkmcnt(0)" ::: "memory");             \
    } else {                                                                    \
        asm volatile("s_waitcnt vmcnt(0) lgkmcnt(0)" ::: "memory");             \
    }                                                                           \
    __builtin_amdgcn_sched_barrier(0);                                          \
    __builtin_amdgcn_s_barrier();                                               \
    __builtin_amdgcn_sched_barrier(0);                                          \
    if (tid < 32) srow[_pp ^ 1][tid] = 0.f;  /* for body t+1; fenced by barriers */ \
    /* ---- scores: tanh(x@W1+b1)@W2 ; A from XC (f32+cvt), B from regs ---- */ \
    f32x4 acc[2][4];                                                            \
    _Pragma("unroll")                                                           \
    for (int _m = 0; _m < 2; ++_m)                                              \
        _Pragma("unroll")                                                       \
        for (int _n = 0; _n < 4; ++_n) acc[_m][_n] = (f32x4){0.f, 0.f, 0.f, 0.f}; \
    __builtin_amdgcn_s_setprio(1);                                              \
    _Pragma("unroll")                                                           \
    for (int _kk = 0; _kk < 8; ++_kk) {                                         \
        bf16x8 _afr[2];                                                         \
        _Pragma("unroll")                                                       \
        for (int _m = 0; _m < 2; ++_m) {                                        \
            const int _rr = 16 * _m + l15;                                      \
            const int _cc = 4 * _kk + g4;                                       \
            const int _o0 = xf_off(_cc, _rr, 0);                                \
            const float4 _f0 = *reinterpret_cast<const float4*>((const char*)(XC) + _o0); \
            const float4 _f1 = *reinterpret_cast<const float4*>((const char*)(XC) + (_o0 ^ 16)); \
            uint4 _u;                                                           \
            _u.x = cvt_pk_bf16(_f0.x, _f0.y); _u.y = cvt_pk_bf16(_f0.z, _f0.w); \
            _u.z = cvt_pk_bf16(_f1.x, _f1.y); _u.w = cvt_pk_bf16(_f1.z, _f1.w); \
            _afr[_m] = *reinterpret_cast<bf16x8*>(&_u);                         \
        }                                                                       \
        _Pragma("unroll")                                                       \
        for (int _m = 0; _m < 2; ++_m)                                          \
            _Pragma("unroll")                                                   \
            for (int _n = 0; _n < 4; ++_n)                                      \
                acc[_m][_n] = __builtin_amdgcn_mfma_f32_16x16x32_bf16(          \
                    _afr[_m], bfr[_kk * 4 + _n], acc[_m][_n], 0, 0, 0);         \
    }                                                                           \
    __builtin_amdgcn_s_setprio(0);                                              \
    /* ---- epilogue: +b1, tanh, *W2, 16-lane reduce, LDS-atomic scatter ---- */ \
    {                                                                           \
        float _part[2][4];                                                      \
        _Pragma("unroll")                                                       \
        for (int _m = 0; _m < 2; ++_m)                                          \
            _Pragma("unroll")                                                   \
            for (int _r = 0; _r < 4; ++_r) _part[_m][_r] = 0.f;                 \
        _Pragma("unroll")                                                       \
        for (int _n = 0; _n < 4; ++_n)                                          \
            _Pragma("unroll")                                                   \
            for (int _m = 0; _m < 2; ++_m)                                      \
                _Pragma("unroll")                                               \
                for (int _r = 0; _r < 4; ++_r) {                                \
                    float _h = fast_tanh(acc[_m][_n][_r] + b1v[_n]);            \
                    _part[_m][_r] += _h * w2v[_n];                              \
                }                                                               \
        _Pragma("unroll")                                                       \
        for (int _m = 0; _m < 2; ++_m)                                          \
            _Pragma("unroll")                                                   \
            for (int _r = 0; _r < 4; ++_r) {                                    \
                float _p = _part[_m][_r];                                       \
                _p += __shfl_xor(_p, 8, 16); _p += __shfl_xor(_p, 4, 16);       \
                _p += __shfl_xor(_p, 2, 16); _p += __shfl_xor(_p, 1, 16);       \
                if (l15 == 0) atomicAdd(&srow[_pp][16 * _m + 4 * g4 + _r], _p); \
            }                                                                   \
    }                                                                           \
    asm volatile("s_waitcnt lgkmcnt(0)" ::: "memory");                          \
    __builtin_amdgcn_sched_barrier(0);                                          \
    __builtin_amdgcn_s_barrier();                                               \
    __builtin_amdgcn_sched_barrier(0);                                          \
    /* ---- pool prep: hoisted per-row exp (b2 dropped: cancels in attn) ---- */ \
    float _ev[8];                                                               \
    _Pragma("unroll")                                                           \
    for (int _it = 0; _it < 8; ++_it) {                                         \
        const int _r = 4 * _it + w;                                             \
        const float _s = srow[_pp][_r];                                         \
        _ev[_it] = (_row0 + _r < N)                                             \
                 ? __builtin_amdgcn_exp2f(_s * 1.4426950408889634f) : 0.f;      \
    }                                                                           \
    POOL(XC);                                                                   \
    asm volatile("s_waitcnt lgkmcnt(0)" ::: "memory");                          \
    __builtin_amdgcn_sched_barrier(0);                                          \
    __builtin_amdgcn_s_barrier();                                               \
    __builtin_amdgcn_sched_barrier(0);                                          \
    ++t;                                                                        \
} while (0)

// ---------------------------------------------------------------------------
// Persistent fused kernel: R5 structure (async gload_lds dbuf staging, W1p
// quarter cached in 128 VGPRs, exact-f32 LDS pooling) with the score
// broadcast rebuilt on LDS float atomics + inline exp (one fewer barrier,
// no 224-idle-lane phase) and setprio around the MFMA cluster.
// ---------------------------------------------------------------------------
__global__ void __launch_bounds__(256, 2)
fused_k(const float* __restrict__ x,
        const unsigned short* __restrict__ W1p,
        const float* __restrict__ b1,
        const float* __restrict__ W2,
        const float* __restrict__ b2,
        const int* __restrict__ batch,
        int N, int NT,
        float* __restrict__ accb, float* __restrict__ den) {
    __shared__ __align__(16) char Xf0[32768];
    __shared__ __align__(16) char Xf1[32768];
    __shared__ __align__(16) float red[4][256];
    __shared__ float srow[2][32];
    __shared__ int   gmin4[4];
    __shared__ float denw[4];

    const int tid = threadIdx.x;
    const int w   = tid >> 6;
    const int l   = tid & 63;
    const int l15 = l & 15;
    const int g4  = l >> 4;

    const int tpb = (NT + NBLK - 1) / NBLK;
    int t = blockIdx.x * tpb;
    const int t1 = min(NT, t + tpb);
    if (t >= t1) return;

    // cache this wave's W1p quarter (cols 64w..64w+63): 32 x bf16x8 = 128 VGPR
    bf16x8 bfr[32];
    #pragma unroll
    for (int kk = 0; kk < 8; ++kk)
        #pragma unroll
        for (int n = 0; n < 4; ++n)
            bfr[kk * 4 + n] = *reinterpret_cast<const bf16x8*>(
                W1p + (size_t)(((kk * 16) + (w * 4 + n)) * 64 + l) * 8);

    float b1v[4], w2v[4];
    #pragma unroll
    for (int n = 0; n < 4; ++n) {
        int col = 64 * w + 16 * n + l15;
        b1v[n] = b1[col];
        w2v[n] = W2[col];
    }

    // prologue: stage first tile into Xf0; zero both srow parities
    STAGE(Xf0, t);
    if (tid < 64) srow[tid >> 5][tid & 31] = 0.f;

    float4 a4 = make_float4(0.f, 0.f, 0.f, 0.f);
    float den_p = 0.f;
    int g_cur = -1;
    int gnv = 0;
    int bg[8];   // kernel scope: final FLUSHX uses last body's values

    while (true) {
        BODY(Xf0, Xf1);
        if (t >= t1) break;
        BODY(Xf1, Xf0);
        if (t >= t1) break;
    }

    // final flush of the last graph
    FLUSHX();
}

// ---------------------------------------------------------------------------
__global__ void __launch_bounds__(256)
norm_k(const float* __restrict__ accb, const float* __restrict__ den,
       float* __restrict__ out) {
    int g = blockIdx.x;
    float dv = den[g];
    float inv = (dv > 0.f) ? 1.0f / dv : 0.f;
    out[(size_t)g * D + threadIdx.x] = accb[(size_t)g * D + threadIdx.x] * inv;
}

// ---------------------------------------------------------------------------
extern "C" void kernel_launch(void* const* d_in, const int* in_sizes, int n_in,
                              void* d_out, int out_size, void* d_ws, size_t ws_size,
                              hipStream_t stream) {
    const float* x     = (const float*)d_in[0];
    const int*   batch = (const int*)d_in[1];
    const float* W1    = (const float*)d_in[3];
    const float* b1    = (const float*)d_in[4];
    const float* W2    = (const float*)d_in[5];
    const float* b2    = (const float*)d_in[6];
    float* out = (float*)d_out;

    const int N = in_sizes[0] / D;
    const int G = out_size / D;
    const int NT = (N + ROWS - 1) / ROWS;

    char* ws = (char*)d_ws;
    unsigned short* W1p = (unsigned short*)ws;               // 128 KB
    float* accb = (float*)(ws + 131072);                     // G*D*4 bytes
    float* den  = (float*)(ws + 131072 + (size_t)G * D * 4); // G*4, contiguous

    zero_k<<<dim3((G * D + G + 255) / 256), dim3(256), 0, stream>>>(accb, G * D + G);
    pack_w1_k<<<dim3(256), dim3(256), 0, stream>>>(W1, W1p);
    fused_k<<<dim3(min(NBLK, NT)), dim3(256), 0, stream>>>(x, W1p, b1, W2, b2, batch,
                                                           N, NT, accb, den);
    norm_k<<<dim3(G), dim3(256), 0, stream>>>(accb, den, out);
}